// Round 1
// baseline (334.424 us; speedup 1.0000x reference)
//
#include <hip/hip_runtime.h>
#include <stdint.h>

// Problem constants (match reference)
#define M_PRED 100
#define N_GT 20
#define IMG_H 800
#define IMG_W 800
#define IOU_THR_F 0.5f
#define SCORE_THR_F 0.05f

// ---------------------------------------------------------------------------
// Kernel 1: IoU + stable score-descending greedy matching (faithful replica,
// including the reference's `gtm <= 0` availability quirk). Single block.
// Writes gtm[N] to workspace, and the two small outputs (flags, scores).
// ---------------------------------------------------------------------------
__global__ __launch_bounds__(256) void match_kernel(
    const float* __restrict__ pred_boxes,   // [M,4] xyxy
    const float* __restrict__ pred_scores,  // [M]
    const float* __restrict__ mask_score,   // [M]
    const float* __restrict__ gt_boxes,     // [N,4] xyxy
    float* __restrict__ out_flags,          // [N]
    float* __restrict__ out_scores,         // [N]
    int* __restrict__ gtm_out)              // [N] workspace
{
    __shared__ float s_iou[M_PRED * N_GT];
    __shared__ float s_pb[M_PRED * 4];
    __shared__ float s_gb[N_GT * 4];
    __shared__ float s_scores[M_PRED];
    __shared__ int   s_order[M_PRED];   // stable argsort(-scores)
    __shared__ int   s_cand[M_PRED];    // candidate flag per pred
    __shared__ int   s_order2[M_PRED];  // compacted candidate order
    __shared__ int   s_ncand;

    const int tid = threadIdx.x;

    // Stage small inputs into LDS
    for (int t = tid; t < M_PRED * 4; t += 256) s_pb[t] = pred_boxes[t];
    for (int t = tid; t < N_GT * 4;   t += 256) s_gb[t] = gt_boxes[t];
    for (int t = tid; t < M_PRED;     t += 256) s_scores[t] = pred_scores[t];
    __syncthreads();

    // Pairwise IoU [M,N] (exact replica of reference arithmetic, f32)
    for (int t = tid; t < M_PRED * N_GT; t += 256) {
        int i = t / N_GT, j = t - i * N_GT;
        float ax0 = s_pb[i * 4 + 0], ay0 = s_pb[i * 4 + 1];
        float ax1 = s_pb[i * 4 + 2], ay1 = s_pb[i * 4 + 3];
        float bx0 = s_gb[j * 4 + 0], by0 = s_gb[j * 4 + 1];
        float bx1 = s_gb[j * 4 + 2], by1 = s_gb[j * 4 + 3];
        float area1 = (ax1 - ax0) * (ay1 - ay0);
        float area2 = (bx1 - bx0) * (by1 - by0);
        float lx = fmaxf(ax0, bx0), ly = fmaxf(ay0, by0);
        float rx = fminf(ax1, bx1), ry = fminf(ay1, by1);
        float w = fmaxf(rx - lx, 0.0f), h = fmaxf(ry - ly, 0.0f);
        float inter = w * h;
        float uni = area1 + area2 - inter;
        s_iou[t] = inter / fmaxf(uni, 1e-6f);
    }
    __syncthreads();

    // Stable descending rank sort (matches jnp.argsort(-scores)) + candidate
    // pre-filter: a pred can only ever match if some iou >= THR and its score
    // passes; availability shrinking can't add matches, so this is sound.
    if (tid < M_PRED) {
        float si = s_scores[tid];
        int r = 0;
        for (int k = 0; k < M_PRED; ++k) {
            float sk = s_scores[k];
            r += (sk > si || (sk == si && k < tid)) ? 1 : 0;
        }
        s_order[r] = tid;
        float mx = 0.0f;
        for (int j = 0; j < N_GT; ++j) mx = fmaxf(mx, s_iou[tid * N_GT + j]);
        s_cand[tid] = (si >= SCORE_THR_F && mx >= IOU_THR_F) ? 1 : 0;
    }
    __syncthreads();

    // Compact candidate list in score order (serial, cheap: ~100 LDS ops)
    if (tid == 0) {
        int cnt = 0;
        for (int r = 0; r < M_PRED; ++r) {
            int i = s_order[r];
            if (s_cand[i]) s_order2[cnt++] = i;
        }
        s_ncand = cnt;
    }
    __syncthreads();

    // Wave-parallel greedy: lane j (< N_GT) owns gtm[j] in a register.
    // Per iteration: 1 LDS read + 6-step shfl_xor max-reduce on packed u64.
    // Key = (float bits << 32) | (63 - lane) -> max picks largest iou,
    // exact ties pick smallest j (replicates jnp.argmax first-max rule).
    if (tid < 64) {
        const int lane = tid;
        const bool is_gt = lane < N_GT;
        int gtm_j = -1;
        const int nc = s_ncand;
        for (int r = 0; r < nc; ++r) {
            int icur = s_order2[r];
            float vr = is_gt ? s_iou[icur * N_GT + lane] : 0.0f;
            // NOTE: reference availability check is `gtm <= 0` (its quirk):
            // a GT matched to pred index 0 remains available.
            bool valid = is_gt && (gtm_j <= 0) && (vr >= IOU_THR_F);
            unsigned long long key = valid
                ? ((((unsigned long long)__float_as_uint(vr)) << 32) |
                   (unsigned long long)(63 - lane))
                : 0ull;
            #pragma unroll
            for (int d = 1; d < 64; d <<= 1) {
                unsigned long long o = __shfl_xor(key, d, 64);
                key = (o > key) ? o : key;
            }
            if (key != 0ull) {
                int bj = 63 - (int)(key & 0xffffffffull);
                if (lane == bj) gtm_j = icur;
            }
        }
        if (is_gt) {
            gtm_out[lane] = gtm_j;
            bool matched = gtm_j > -1;
            int idx = matched ? gtm_j : 0;
            out_flags[lane]  = matched ? mask_score[idx] : 0.0f;
            out_scores[lane] = matched ? s_scores[idx]   : 0.0f;
        }
    }
}

// ---------------------------------------------------------------------------
// Kernel 2: stream matched masks to output (or zero-fill). Memory-bound.
// 800*800 floats = 160,000 float4 per mask; grid (625, N_GT) x 256 threads
// puts exactly one float4 per thread, fully coalesced.
// ---------------------------------------------------------------------------
__global__ __launch_bounds__(256) void scatter_kernel(
    const float4* __restrict__ pred_masks,  // [M, H*W/4]
    const int* __restrict__ gtm,            // [N]
    float4* __restrict__ out)               // [N, H*W/4]
{
    const int j = blockIdx.y;                       // gt index (uniform)
    const int idx = blockIdx.x * 256 + threadIdx.x; // 0 .. 159999
    const int per = (IMG_H * IMG_W) / 4;            // 160000
    int g = gtm[j];
    float4 v = make_float4(0.0f, 0.0f, 0.0f, 0.0f);
    if (g > -1) v = pred_masks[(size_t)g * per + idx];
    out[(size_t)j * per + idx] = v;
}

extern "C" void kernel_launch(void* const* d_in, const int* in_sizes, int n_in,
                              void* d_out, int out_size, void* d_ws, size_t ws_size,
                              hipStream_t stream) {
    const float* pred_boxes  = (const float*)d_in[0];  // [100,4]
    const float* pred_scores = (const float*)d_in[1];  // [100]
    const float* mask_score  = (const float*)d_in[2];  // [100]
    const float* pred_masks  = (const float*)d_in[3];  // [100,800,800]
    const float* gt_boxes    = (const float*)d_in[4];  // [20,4]
    float* out = (float*)d_out;
    int* gtm_ws = (int*)d_ws;

    float* out_flags  = out + (size_t)N_GT * IMG_H * IMG_W;  // [20]
    float* out_scores = out_flags + N_GT;                    // [20]

    match_kernel<<<1, 256, 0, stream>>>(pred_boxes, pred_scores, mask_score,
                                        gt_boxes, out_flags, out_scores, gtm_ws);

    dim3 grid((IMG_H * IMG_W / 4) / 256, N_GT);  // (625, 20)
    scatter_kernel<<<grid, dim3(256), 0, stream>>>(
        (const float4*)pred_masks, gtm_ws, (float4*)out);
}

// Round 3
// 332.509 us; speedup vs baseline: 1.0058x; 1.0058x over previous
//
#include <hip/hip_runtime.h>
#include <stdint.h>

// Problem constants (match reference)
#define M_PRED 100
#define N_GT 20
#define IMG_H 800
#define IMG_W 800
#define IOU_THR_F 0.5f
#define SCORE_THR_F 0.05f

typedef float f32x4 __attribute__((ext_vector_type(4)));

// ---------------------------------------------------------------------------
// Kernel 1: IoU + stable score-descending greedy matching (faithful replica,
// including the reference's `gtm <= 0` availability quirk). Single block,
// 128 threads. Greedy inner loop: 32-lane f32 shfl max-reduce (5 shuffles)
// + ballot for lowest-j tie-break (replicates jnp.argmax first-max rule).
// ---------------------------------------------------------------------------
__global__ __launch_bounds__(128) void match_kernel(
    const float* __restrict__ pred_boxes,   // [M,4] xyxy
    const float* __restrict__ pred_scores,  // [M]
    const float* __restrict__ mask_score,   // [M]
    const float* __restrict__ gt_boxes,     // [N,4] xyxy
    float* __restrict__ out_flags,          // [N]
    float* __restrict__ out_scores,         // [N]
    int* __restrict__ gtm_out)              // [N] workspace
{
    __shared__ float s_iou[M_PRED * N_GT];
    __shared__ float s_pb[M_PRED * 4];
    __shared__ float s_gb[N_GT * 4];
    __shared__ float s_scores[M_PRED];
    __shared__ int   s_order[M_PRED];   // stable argsort(-scores)
    __shared__ int   s_cand[M_PRED];    // candidate flag per pred
    __shared__ int   s_order2[M_PRED];  // compacted candidate order
    __shared__ int   s_ncand;

    const int tid = threadIdx.x;

    // Stage small inputs into LDS
    for (int t = tid; t < M_PRED * 4; t += 128) s_pb[t] = pred_boxes[t];
    if (tid < N_GT * 4) s_gb[tid] = gt_boxes[tid];
    if (tid < M_PRED)   s_scores[tid] = pred_scores[tid];
    __syncthreads();

    // Pairwise IoU [M,N] (exact replica of reference arithmetic, f32)
    for (int t = tid; t < M_PRED * N_GT; t += 128) {
        int i = t / N_GT, j = t - i * N_GT;
        float ax0 = s_pb[i * 4 + 0], ay0 = s_pb[i * 4 + 1];
        float ax1 = s_pb[i * 4 + 2], ay1 = s_pb[i * 4 + 3];
        float bx0 = s_gb[j * 4 + 0], by0 = s_gb[j * 4 + 1];
        float bx1 = s_gb[j * 4 + 2], by1 = s_gb[j * 4 + 3];
        float area1 = (ax1 - ax0) * (ay1 - ay0);
        float area2 = (bx1 - bx0) * (by1 - by0);
        float lx = fmaxf(ax0, bx0), ly = fmaxf(ay0, by0);
        float rx = fminf(ax1, bx1), ry = fminf(ay1, by1);
        float w = fmaxf(rx - lx, 0.0f), h = fmaxf(ry - ly, 0.0f);
        float inter = w * h;
        float uni = area1 + area2 - inter;
        s_iou[t] = inter / fmaxf(uni, 1e-6f);
    }
    __syncthreads();

    // Stable descending rank sort (matches jnp.argsort(-scores)) + candidate
    // pre-filter: a pred can only ever match if some iou >= THR and its score
    // passes; availability shrinking can't add matches, so this is sound.
    if (tid < M_PRED) {
        float si = s_scores[tid];
        int r = 0;
        for (int k = 0; k < M_PRED; ++k) {
            float sk = s_scores[k];
            r += (sk > si || (sk == si && k < tid)) ? 1 : 0;
        }
        s_order[r] = tid;
        float mx = 0.0f;
        for (int j = 0; j < N_GT; ++j) mx = fmaxf(mx, s_iou[tid * N_GT + j]);
        s_cand[tid] = (si >= SCORE_THR_F && mx >= IOU_THR_F) ? 1 : 0;
    }
    __syncthreads();

    // Compact candidate list in score order (serial, ~100 dependent LDS ops)
    if (tid == 0) {
        int cnt = 0;
        for (int r = 0; r < M_PRED; ++r) {
            int i = s_order[r];
            if (s_cand[i]) s_order2[cnt++] = i;
        }
        s_ncand = cnt;
    }
    __syncthreads();

    // Greedy: lane j (< N_GT) owns gtm[j] in a register. Per candidate:
    // 1 LDS read + 5x f32 shfl_xor (width 32) + 1 ballot. Valid values are
    // >= IOU_THR > 0, so -1.0f is a safe "invalid" sentinel.
    if (tid < 32) {
        const int lane = tid;
        const bool is_gt = lane < N_GT;
        int gtm_j = -1;
        const int nc = s_ncand;
        for (int r = 0; r < nc; ++r) {
            int icur = s_order2[r];
            float v = is_gt ? s_iou[icur * N_GT + lane] : -1.0f;
            // Reference availability check is `gtm <= 0` (its quirk): a GT
            // matched to pred index 0 remains available for re-matching.
            bool valid = is_gt && (gtm_j <= 0) && (v >= IOU_THR_F);
            float x = valid ? v : -1.0f;
            #pragma unroll
            for (int d = 1; d < 32; d <<= 1)
                x = fmaxf(x, __shfl_xor(x, d, 32));
            unsigned long long mb = __ballot(valid && (v == x));
            if (mb != 0ull) {
                int bj = (int)__builtin_ctzll(mb);  // lowest j achieving max
                if (lane == bj) gtm_j = icur;
            }
        }
        if (is_gt) {
            gtm_out[lane] = gtm_j;
            bool matched = gtm_j > -1;
            int idx = matched ? gtm_j : 0;
            out_flags[lane]  = matched ? mask_score[idx] : 0.0f;
            out_scores[lane] = matched ? s_scores[idx]   : 0.0f;
        }
    }
}

// ---------------------------------------------------------------------------
// Kernel 2: stream matched masks to output (or zero-fill). Memory-bound:
// 51.2 MB read (matched rows) + 51.2 MB write -> ~16 us floor @6.3 TB/s.
// One float4 per thread, fully coalesced; nontemporal (touch-once data).
// ---------------------------------------------------------------------------
__global__ __launch_bounds__(256) void scatter_kernel(
    const f32x4* __restrict__ pred_masks,  // [M, H*W/4]
    const int* __restrict__ gtm,           // [N]
    f32x4* __restrict__ out)               // [N, H*W/4]
{
    const int j = blockIdx.y;                       // gt index (uniform)
    const int idx = blockIdx.x * 256 + threadIdx.x; // 0 .. 159999
    const int per = (IMG_H * IMG_W) / 4;            // 160000
    int g = gtm[j];                                 // uniform -> scalar load
    f32x4 v = {0.0f, 0.0f, 0.0f, 0.0f};
    if (g > -1) v = __builtin_nontemporal_load(&pred_masks[(size_t)g * per + idx]);
    __builtin_nontemporal_store(v, &out[(size_t)j * per + idx]);
}

extern "C" void kernel_launch(void* const* d_in, const int* in_sizes, int n_in,
                              void* d_out, int out_size, void* d_ws, size_t ws_size,
                              hipStream_t stream) {
    const float* pred_boxes  = (const float*)d_in[0];  // [100,4]
    const float* pred_scores = (const float*)d_in[1];  // [100]
    const float* mask_score  = (const float*)d_in[2];  // [100]
    const float* pred_masks  = (const float*)d_in[3];  // [100,800,800]
    const float* gt_boxes    = (const float*)d_in[4];  // [20,4]
    float* out = (float*)d_out;
    int* gtm_ws = (int*)d_ws;

    float* out_flags  = out + (size_t)N_GT * IMG_H * IMG_W;  // [20]
    float* out_scores = out_flags + N_GT;                    // [20]

    match_kernel<<<1, 128, 0, stream>>>(pred_boxes, pred_scores, mask_score,
                                        gt_boxes, out_flags, out_scores, gtm_ws);

    dim3 grid((IMG_H * IMG_W / 4) / 256, N_GT);  // (625, 20)
    scatter_kernel<<<grid, dim3(256), 0, stream>>>(
        (const f32x4*)pred_masks, gtm_ws, (f32x4*)out);
}